// Round 9
// baseline (279.941 us; speedup 1.0000x reference)
//
#include <hip/hip_runtime.h>
#include <hip/hip_bf16.h>

// Problem constants (fixed by the reference)
#define NROWS 65536
#define DIM   512
#define H1DIM 1024
#define H2DIM 512
#define EPSC  0.15f
#define DELTA 0.05f
#define NGRP  8
#define PCAP  10240   // per-group LDS compaction capacity (actual ~8192)

typedef __bf16 bf16x8 __attribute__((ext_vector_type(8)));
typedef float  f32x4  __attribute__((ext_vector_type(4)));

__device__ __forceinline__ void gload16(const void* g, void* lds) {
  __builtin_amdgcn_global_load_lds((__attribute__((address_space(1))) const unsigned int*)g,
                                   (__attribute__((address_space(3))) unsigned int*)lds,
                                   16, 0, 0);
}

// ---------------- transpose + fp32->bf16 weight conversion ----------------
// src [R][C] fp32 row-major  ->  dst [C][R] bf16 row-major
__global__ void k_tcvt(const float* __restrict__ src, __bf16* __restrict__ dst, int R, int C) {
  __shared__ float tile[32][33];
  const int bi = blockIdx.x * 32;     // row base in src
  const int bj = blockIdx.y * 32;     // col base in src
  const int tx = threadIdx.x, ty = threadIdx.y;   // block (32,8)
  #pragma unroll
  for (int r = ty; r < 32; r += 8)
    tile[r][tx] = src[(size_t)(bi + r) * C + bj + tx];
  __syncthreads();
  #pragma unroll
  for (int r = ty; r < 32; r += 8)
    dst[(size_t)(bj + r) * R + bi + tx] = (__bf16)tile[tx][r];
}

// ---------------- x fp32 -> bf16 (2x float4 -> bf16x8) + optional y_u zeroing ----------------
__global__ __launch_bounds__(256) void k_cvt_x(const float4* __restrict__ x4,
                                               bf16x8* __restrict__ xb8, int n8,
                                               float* __restrict__ y_u, int zn) {
  const int stride = gridDim.x * blockDim.x;
  for (int i = blockIdx.x * blockDim.x + threadIdx.x; i < n8; i += stride) {
    const float4 a = x4[2 * i];
    const float4 b = x4[2 * i + 1];
    bf16x8 v;
    v[0] = (__bf16)a.x; v[1] = (__bf16)a.y; v[2] = (__bf16)a.z; v[3] = (__bf16)a.w;
    v[4] = (__bf16)b.x; v[5] = (__bf16)b.y; v[6] = (__bf16)b.z; v[7] = (__bf16)b.w;
    xb8[i] = v;
  }
  for (int j = blockIdx.x * blockDim.x + threadIdx.x; j < zn; j += stride)
    y_u[j] = 0.f;
}

// ============ R6 GEMMs (best measured structure): 256x256 / BK=64 / 8-wave dbuf ============
// T2 swizzle (both-sides): linear gload_lds dest + inverse-swizzled source col
// (slot' = (l&7)^((l>>3)&7)) + read byte-XOR ((lr&7)<<4).
// T4: STAGE(t+1) issued before s_waitcnt vmcnt(8) — 8 loads in flight across barrier.

// ---------------- GEMM1: h1 = relu(xb @ W1 + b1), bf16 in/out ----------------
// Grid 1-D: (Mc/256)*4 blocks, XCD-chunked swizzle, n-fastest.
__global__ __launch_bounds__(512, 2) void k_gemm1(const __bf16* __restrict__ xb,
                                                  const __bf16* __restrict__ w1t,
                                                  const float* __restrict__ b1,
                                                  __bf16* __restrict__ h1) {
  __shared__ __align__(16) __bf16 As[2][256 * 64];
  __shared__ __align__(16) __bf16 Bs[2][256 * 64];
  const int tid = threadIdx.x;
  const int w = tid >> 6, l = tid & 63;
  const int mt   = (int)gridDim.x >> 2;   // m-tiles (4 col-tiles)
  const int mper = mt >> 3;               // m-tiles per XCD
  const int xcd  = blockIdx.x & 7;
  const int idx  = blockIdx.x >> 3;
  const int brow = (xcd * mper + (idx >> 2)) * 256;  // chunk-local
  const int bcol = (idx & 3) * 256;
  const int lr = l & 15, lk = l >> 4;
  const int wm = w >> 2, wn = w & 3;          // 2M x 4N wave grid
  const int mbase = wm * 128, nbase = wn * 64;
  const int srow = w * 32 + (l >> 3);         // staging row (+ t*8)
  const int scol = (((l & 7) ^ ((l >> 3) & 7)) * 8);  // T2 inverse-swizzled source col
  const int swz  = (lr & 7) << 4;             // T2 read swizzle (byte XOR)
  const int NT = DIM / 64;                    // 8 K-steps
  f32x4 acc[8][4] = {};

  #define STAGE1(KT, BUF) do { \
    _Pragma("unroll") for (int t_ = 0; t_ < 4; ++t_) { \
      gload16(xb  + (size_t)(brow + srow + t_ * 8) * DIM + (KT) + scol, \
              As[BUF] + (w * 32 + t_ * 8) * 64); \
      gload16(w1t + (size_t)(bcol + srow + t_ * 8) * DIM + (KT) + scol, \
              Bs[BUF] + (w * 32 + t_ * 8) * 64); } } while (0)
  #define COMPUTE1(BUF) do { \
    _Pragma("unroll") for (int kk = 0; kk < 64; kk += 32) { \
      bf16x8 af[8], bq[4]; \
      _Pragma("unroll") for (int m = 0; m < 8; ++m) \
        af[m] = *(const bf16x8*)((const char*)(As[BUF]) + \
                 ((((mbase + m * 16 + lr) * 128) + kk * 2 + lk * 16) ^ swz)); \
      _Pragma("unroll") for (int nn = 0; nn < 4; ++nn) \
        bq[nn] = *(const bf16x8*)((const char*)(Bs[BUF]) + \
                 ((((nbase + nn * 16 + lr) * 128) + kk * 2 + lk * 16) ^ swz)); \
      __builtin_amdgcn_s_setprio(1); \
      _Pragma("unroll") for (int m = 0; m < 8; ++m) \
        _Pragma("unroll") for (int nn = 0; nn < 4; ++nn) \
          acc[m][nn] = __builtin_amdgcn_mfma_f32_16x16x32_bf16(af[m], bq[nn], acc[m][nn], 0, 0, 0); \
      __builtin_amdgcn_s_setprio(0); \
    } } while (0)

  STAGE1(0, 0);
  int cur = 0;
  for (int t = 0; t < NT - 1; ++t) {
    STAGE1((t + 1) * 64, cur ^ 1);                      // 8 loads stay in flight
    asm volatile("s_waitcnt vmcnt(8)" ::: "memory");    // tile t (oldest 8) done
    __builtin_amdgcn_s_barrier();                       // ready-barrier
    COMPUTE1(cur);
    __builtin_amdgcn_s_barrier();                       // free-barrier
    cur ^= 1;
  }
  asm volatile("s_waitcnt vmcnt(0)" ::: "memory");
  __builtin_amdgcn_s_barrier();
  COMPUTE1(cur);

  #undef STAGE1
  #undef COMPUTE1

  // epilogue: bias + relu + bf16 store
  #pragma unroll
  for (int nn = 0; nn < 4; ++nn) {
    const int col = bcol + nbase + nn * 16 + lr;
    const float bias = b1[col];
    #pragma unroll
    for (int m = 0; m < 8; ++m) {
      const int row = brow + mbase + m * 16 + lk * 4;   // chunk-local
      #pragma unroll
      for (int j = 0; j < 4; ++j) {
        float v = acc[m][nn][j] + bias;
        v = fmaxf(v, 0.f);
        h1[(size_t)(row + j) * H1DIM + col] = (__bf16)v;
      }
    }
  }
}

// ---------------- GEMM2 fused: y_u += relu(h1 @ W2 + b2) @ Wf ----------------
// Same structure. Grid 1-D: (Mc/256)*2 blocks.
__global__ __launch_bounds__(512, 2) void k_gemm2(const __bf16* __restrict__ h1,
                                                  const __bf16* __restrict__ w2t,
                                                  const float* __restrict__ b2,
                                                  const float* __restrict__ wf,
                                                  float* __restrict__ y_u, int row0) {
  __shared__ __align__(16) __bf16 As[2][256 * 64];
  __shared__ __align__(16) __bf16 Bs[2][256 * 64];
  __shared__ float yred[256];
  const int tid = threadIdx.x;
  const int w = tid >> 6, l = tid & 63;
  const int mt   = (int)gridDim.x >> 1;   // m-tiles (2 col-tiles)
  const int mper = mt >> 3;
  const int xcd  = blockIdx.x & 7;
  const int idx  = blockIdx.x >> 3;
  const int brow = (xcd * mper + (idx >> 1)) * 256;  // chunk-local
  const int n0   = (idx & 1) * 256;
  const int lr = l & 15, lk = l >> 4;
  const int wm = w >> 2, wn = w & 3;
  const int mbase = wm * 128, nbase = wn * 64;
  const int srow = w * 32 + (l >> 3);
  const int scol = (((l & 7) ^ ((l >> 3) & 7)) * 8);  // T2 inverse-swizzled source col
  const int swz  = (lr & 7) << 4;                     // T2 read swizzle
  const int NT = H1DIM / 64;              // 16 K-steps
  f32x4 acc[8][4] = {};

  #define STAGE2(KT, BUF) do { \
    _Pragma("unroll") for (int t_ = 0; t_ < 4; ++t_) { \
      gload16(h1  + (size_t)(brow + srow + t_ * 8) * H1DIM + (KT) + scol, \
              As[BUF] + (w * 32 + t_ * 8) * 64); \
      gload16(w2t + (size_t)(n0   + srow + t_ * 8) * H1DIM + (KT) + scol, \
              Bs[BUF] + (w * 32 + t_ * 8) * 64); } } while (0)
  #define COMPUTE2(BUF) do { \
    _Pragma("unroll") for (int kk = 0; kk < 64; kk += 32) { \
      bf16x8 af[8], bq[4]; \
      _Pragma("unroll") for (int m = 0; m < 8; ++m) \
        af[m] = *(const bf16x8*)((const char*)(As[BUF]) + \
                 ((((mbase + m * 16 + lr) * 128) + kk * 2 + lk * 16) ^ swz)); \
      _Pragma("unroll") for (int nn = 0; nn < 4; ++nn) \
        bq[nn] = *(const bf16x8*)((const char*)(Bs[BUF]) + \
                 ((((nbase + nn * 16 + lr) * 128) + kk * 2 + lk * 16) ^ swz)); \
      __builtin_amdgcn_s_setprio(1); \
      _Pragma("unroll") for (int m = 0; m < 8; ++m) \
        _Pragma("unroll") for (int nn = 0; nn < 4; ++nn) \
          acc[m][nn] = __builtin_amdgcn_mfma_f32_16x16x32_bf16(af[m], bq[nn], acc[m][nn], 0, 0, 0); \
      __builtin_amdgcn_s_setprio(0); \
    } } while (0)

  STAGE2(0, 0);
  int cur = 0;
  for (int t = 0; t < NT - 1; ++t) {
    STAGE2((t + 1) * 64, cur ^ 1);
    asm volatile("s_waitcnt vmcnt(8)" ::: "memory");
    __builtin_amdgcn_s_barrier();
    COMPUTE2(cur);
    __builtin_amdgcn_s_barrier();
    cur ^= 1;
  }
  asm volatile("s_waitcnt vmcnt(0)" ::: "memory");
  __builtin_amdgcn_s_barrier();
  COMPUTE2(cur);

  #undef STAGE2
  #undef COMPUTE2

  // epilogue: relu + dot with Wf over this block's 256 h2-columns
  float yacc[8][4] = {};
  #pragma unroll
  for (int nn = 0; nn < 4; ++nn) {
    const int col = n0 + nbase + nn * 16 + lr;
    const float bias = b2[col];
    const float wfv = wf[col];
    #pragma unroll
    for (int m = 0; m < 8; ++m)
      #pragma unroll
      for (int j = 0; j < 4; ++j)
        yacc[m][j] += fmaxf(acc[m][nn][j] + bias, 0.f) * wfv;
  }
  #pragma unroll
  for (int m = 0; m < 8; ++m)
    #pragma unroll
    for (int j = 0; j < 4; ++j) {
      float v = yacc[m][j];
      v += __shfl_xor(v, 1, 64);
      v += __shfl_xor(v, 2, 64);
      v += __shfl_xor(v, 4, 64);
      v += __shfl_xor(v, 8, 64);
      yacc[m][j] = v;
    }
  if (tid < 256) yred[tid] = 0.f;
  __syncthreads();
  if (lr == 0) {
    #pragma unroll
    for (int m = 0; m < 8; ++m)
      #pragma unroll
      for (int j = 0; j < 4; ++j)
        atomicAdd(&yred[mbase + m * 16 + lk * 4 + j], yacc[m][j]);
  }
  __syncthreads();
  if (tid < 256) atomicAdd(&y_u[row0 + brow + tid], yred[tid]);
}

// ---------------- fused projection: compact -> Newton-bisect -> write ----------------
// One block per group. Ballot-compacted (z0, 1/w, idx) in LDS; m(mu) is monotone
// piecewise-linear, so safeguarded Newton converges in <10 evals (12 fixed).
__global__ __launch_bounds__(1024) void k_proj(const float* __restrict__ y_u,
                                               const float* __restrict__ c,
                                               const float* __restrict__ mask,
                                               const float* __restrict__ bfp,
                                               float* __restrict__ out) {
  __shared__ float z0s[PCAP];
  __shared__ float iws[PCAP];
  __shared__ int   idxs[PCAP];
  __shared__ float reds[16], redd[16];
  __shared__ int   gcount;
  const int g = blockIdx.x;
  const int tid = threadIdx.x;
  const int lane = tid & 63;
  const int wid = tid >> 6;
  const float bf0 = bfp[0];
  if (tid == 0) gcount = 0;
  __syncthreads();
  // Phase A: ballot-compact this group's rows into LDS (wave-aggregated alloc)
  for (int i = tid; i < NROWS; i += 1024) {
    const bool in = mask[(size_t)g * NROWS + i] > 0.5f;
    const unsigned long long b = __ballot(in);
    const int pre = __popcll(b & ((1ull << lane) - 1));
    int wbase = 0;
    if (lane == 0 && b) wbase = atomicAdd(&gcount, __popcll(b));
    wbase = __shfl(wbase, 0, 64);
    if (in) {
      const int s = wbase + pre;
      if (s < PCAP) {
        const float cv = c[i];
        z0s[s]  = (y_u[i] + bf0) / cv - 1.f;
        iws[s]  = 1.f / (cv * cv);
        idxs[s] = i;
      }
    }
  }
  __syncthreads();
  int n = gcount; if (n > PCAP) n = PCAP;
  const float inv_n = (n > 0) ? 1.f / (float)n : 0.f;
  // registers: up to 10 entries/thread (PCAP/1024)
  float z0v[10], iwv[10];
  float hmax = -1e30f, hmin = 1e30f;
  #pragma unroll
  for (int t = 0; t < 10; ++t) {
    const int s = t * 1024 + tid;
    if (s < n) {
      z0v[t] = z0s[s]; iwv[t] = iws[s];
      const float wv = 1.f / iwv[t];
      hmax = fmaxf(hmax, (z0v[t] + EPSC) * wv);
      hmin = fminf(hmin, (z0v[t] - EPSC) * wv);
    } else { z0v[t] = 0.f; iwv[t] = 0.f; }
  }
  // joint (sum, sumd) block reduction
  #define RED2(SV, DV) do { \
    _Pragma("unroll") for (int o_ = 32; o_ > 0; o_ >>= 1) { \
      SV += __shfl_xor(SV, o_, 64); DV += __shfl_xor(DV, o_, 64); } \
    if (lane == 0) { reds[wid] = SV; redd[wid] = DV; } \
    __syncthreads(); \
    if (tid < 64) { \
      float a_ = (tid < 16) ? reds[tid] : 0.f; \
      float b_ = (tid < 16) ? redd[tid] : 0.f; \
      _Pragma("unroll") for (int o_ = 32; o_ > 0; o_ >>= 1) { \
        a_ += __shfl_xor(a_, o_, 64); b_ += __shfl_xor(b_, o_, 64); } \
      if (tid == 0) { reds[0] = a_; redd[0] = b_; } \
    } \
    __syncthreads(); \
    SV = reds[0]; DV = redd[0]; \
    __syncthreads(); \
  } while (0)
  #define EVAL2(MU, MS, DS) do { \
    float s_ = 0.f, d_ = 0.f; \
    _Pragma("unroll") for (int t_ = 0; t_ < 10; ++t_) { \
      float zz_ = z0v[t_] - (MU) * iwv[t_]; \
      if (zz_ > EPSC) zz_ = EPSC; \
      else if (zz_ < -EPSC) zz_ = -EPSC; \
      else d_ += iwv[t_]; \
      s_ += zz_; } \
    RED2(s_, d_); \
    MS = s_ * inv_n; DS = d_ * inv_n; \
  } while (0)
  float mu = 0.f;
  if (n > 0) {
    float m0, d0;
    EVAL2(0.f, m0, d0);
    if (fabsf(m0) > DELTA) {
      // bracket: m decreasing in mu; reduce hmax (max) and hmin (min) jointly
      float hx = hmax, hn = -hmin;
      #pragma unroll
      for (int o_ = 32; o_ > 0; o_ >>= 1) {
        hx = fmaxf(hx, __shfl_xor(hx, o_, 64));
        hn = fmaxf(hn, __shfl_xor(hn, o_, 64));
      }
      if (lane == 0) { reds[wid] = hx; redd[wid] = hn; }
      __syncthreads();
      if (tid < 64) {
        float a_ = (tid < 16) ? reds[tid] : -1e30f;
        float b_ = (tid < 16) ? redd[tid] : -1e30f;
        #pragma unroll
        for (int o_ = 32; o_ > 0; o_ >>= 1) {
          a_ = fmaxf(a_, __shfl_xor(a_, o_, 64));
          b_ = fmaxf(b_, __shfl_xor(b_, o_, 64));
        }
        if (tid == 0) { reds[0] = a_; redd[0] = b_; }
      }
      __syncthreads();
      const float hmax_r = reds[0], hmin_r = -redd[0];
      __syncthreads();
      float target, lo, hi;
      if (m0 > 0.f) { target = DELTA;  lo = 0.f;     hi = hmax_r; }
      else          { target = -DELTA; lo = hmin_r;  hi = 0.f;    }
      mu = 0.5f * (lo + hi);
      for (int it = 0; it < 12; ++it) {
        float mm, dd;
        EVAL2(mu, mm, dd);
        if (mm >= target) lo = mu; else hi = mu;
        float nm = (dd > 0.f) ? mu + (mm - target) / dd : 0.5f * (lo + hi);
        if (!(nm > lo && nm < hi)) nm = 0.5f * (lo + hi);
        mu = nm;
      }
    }
  }
  // Phase C: clip + write
  #pragma unroll
  for (int t = 0; t < 10; ++t) {
    const int s = t * 1024 + tid;
    if (s < n) {
      float z = z0v[t] - mu * iwv[t];
      z = fminf(fmaxf(z, -EPSC), EPSC);
      const int ri = idxs[s];
      out[ri] = (z + 1.f) * c[ri];
    }
  }
  #undef RED2
  #undef EVAL2
}

extern "C" void kernel_launch(void* const* d_in, const int* in_sizes, int n_in,
                              void* d_out, int out_size, void* d_ws, size_t ws_size,
                              hipStream_t stream) {
  const float* x    = (const float*)d_in[0];
  const float* W1   = (const float*)d_in[1];
  const float* b1   = (const float*)d_in[2];
  const float* W2   = (const float*)d_in[3];
  const float* b2   = (const float*)d_in[4];
  const float* Wf   = (const float*)d_in[5];
  const float* bfp  = (const float*)d_in[6];
  const float* c    = (const float*)d_in[7];
  const float* mask = (const float*)d_in[8];
  float* out = (float*)d_out;

  char* ws = (char*)d_ws;
  size_t off = 0;
  auto alloc = [&](size_t bytes) -> void* {
    void* p = ws + off;
    off += (bytes + 255) & ~(size_t)255;
    return p;
  };
  __bf16* w1t = (__bf16*)alloc((size_t)H1DIM * DIM * 2);
  __bf16* w2t = (__bf16*)alloc((size_t)H2DIM * H1DIM * 2);
  float* y_u  = (float*)alloc((size_t)NROWS * 4);
  const size_t fixed = off;

  // per-chunk buffers: xb (1 KB/row) + h1 (2 KB/row) = 3 KB/row.
  // Chunk must be a multiple of 2048 rows (256-row tiles, m-tiles % 8 == 0).
  size_t avail = (ws_size > fixed) ? (ws_size - fixed) : 0;
  long long rc = (long long)(avail / ((size_t)(DIM * 2 + H1DIM * 2)));
  rc &= ~2047LL;
  if (rc > 32768) rc = 32768;
  if (rc < 2048) rc = 2048;   // below this ws is insufficient; assume harness gives enough
  const int rows_chunk = (int)rc;
  __bf16* xb = (__bf16*)(ws + fixed);
  __bf16* h1 = (__bf16*)(ws + fixed + (size_t)rows_chunk * DIM * 2);

  k_tcvt<<<dim3(DIM / 32, H1DIM / 32), dim3(32, 8), 0, stream>>>(W1, w1t, DIM, H1DIM);
  k_tcvt<<<dim3(H1DIM / 32, H2DIM / 32), dim3(32, 8), 0, stream>>>(W2, w2t, H1DIM, H2DIM);

  bool first = true;
  for (int r0 = 0; r0 < NROWS; r0 += rows_chunk) {
    const int Mc = (NROWS - r0 < rows_chunk) ? (NROWS - r0) : rows_chunk;
    const int mtiles = Mc / 256;
    const int n8 = Mc * (DIM / 8);
    int cblocks = (n8 + 255) / 256; if (cblocks > 2048) cblocks = 2048;
    k_cvt_x<<<dim3(cblocks), dim3(256), 0, stream>>>(
        (const float4*)(x + (size_t)r0 * DIM), (bf16x8*)xb, n8,
        y_u, first ? NROWS : 0);
    first = false;
    k_gemm1<<<dim3(mtiles * 4), dim3(512), 0, stream>>>(xb, w1t, b1, h1);
    k_gemm2<<<dim3(mtiles * 2), dim3(512), 0, stream>>>(h1, w2t, b2, Wf, y_u, r0);
  }

  k_proj<<<dim3(NGRP), dim3(1024), 0, stream>>>(y_u, c, mask, bfp, out);
}

// Round 10
// 231.687 us; speedup vs baseline: 1.2083x; 1.2083x over previous
//
#include <hip/hip_runtime.h>
#include <hip/hip_bf16.h>

// Problem constants (fixed by the reference)
#define NROWS 65536
#define DIM   512
#define H1DIM 1024
#define H2DIM 512
#define EPSC  0.15f
#define DELTA 0.05f
#define NGRP  8
#define CAPG  16384   // per-group compacted capacity (actual ~8192)

typedef __bf16 bf16x8 __attribute__((ext_vector_type(8)));
typedef float  f32x4  __attribute__((ext_vector_type(4)));

__device__ __forceinline__ void gload16(const void* g, void* lds) {
  __builtin_amdgcn_global_load_lds((__attribute__((address_space(1))) const unsigned int*)g,
                                   (__attribute__((address_space(3))) unsigned int*)lds,
                                   16, 0, 0);
}

// ---------------- transpose + fp32->bf16 weight conversion ----------------
// src [R][C] fp32 row-major  ->  dst [C][R] bf16 row-major
__global__ void k_tcvt(const float* __restrict__ src, __bf16* __restrict__ dst, int R, int C) {
  __shared__ float tile[32][33];
  const int bi = blockIdx.x * 32;     // row base in src
  const int bj = blockIdx.y * 32;     // col base in src
  const int tx = threadIdx.x, ty = threadIdx.y;   // block (32,8)
  #pragma unroll
  for (int r = ty; r < 32; r += 8)
    tile[r][tx] = src[(size_t)(bi + r) * C + bj + tx];
  __syncthreads();
  #pragma unroll
  for (int r = ty; r < 32; r += 8)
    dst[(size_t)(bj + r) * R + bi + tx] = (__bf16)tile[tx][r];
}

// ---------------- x fp32 -> bf16 (2x float4 -> bf16x8) + first-chunk zeroing ----------------
__global__ __launch_bounds__(256) void k_cvt_x(const float4* __restrict__ x4,
                                               bf16x8* __restrict__ xb8, int n8,
                                               float* __restrict__ y_u, int zn,
                                               int* __restrict__ cnt) {
  const int stride = gridDim.x * blockDim.x;
  const int tid0 = blockIdx.x * blockDim.x + threadIdx.x;
  for (int i = tid0; i < n8; i += stride) {
    const float4 a = x4[2 * i];
    const float4 b = x4[2 * i + 1];
    bf16x8 v;
    v[0] = (__bf16)a.x; v[1] = (__bf16)a.y; v[2] = (__bf16)a.z; v[3] = (__bf16)a.w;
    v[4] = (__bf16)b.x; v[5] = (__bf16)b.y; v[6] = (__bf16)b.z; v[7] = (__bf16)b.w;
    xb8[i] = v;
  }
  for (int j = tid0; j < zn; j += stride) y_u[j] = 0.f;
  if (zn > 0 && tid0 < NGRP) cnt[tid0] = 0;
}

// ============ R6 GEMMs (best measured structure): 256x256 / BK=64 / 8-wave dbuf ============
// T2 swizzle (both-sides): linear gload_lds dest + inverse-swizzled source col
// (slot' = (l&7)^((l>>3)&7)) + read byte-XOR ((lr&7)<<4).
// T4: STAGE(t+1) issued before s_waitcnt vmcnt(8) — 8 loads in flight across barrier.

// ---------------- GEMM1: h1 = relu(xb @ W1 + b1), bf16 in/out ----------------
// Grid 1-D: (Mc/256)*4 blocks, XCD-chunked swizzle, n-fastest.
__global__ __launch_bounds__(512, 2) void k_gemm1(const __bf16* __restrict__ xb,
                                                  const __bf16* __restrict__ w1t,
                                                  const float* __restrict__ b1,
                                                  __bf16* __restrict__ h1) {
  __shared__ __align__(16) __bf16 As[2][256 * 64];
  __shared__ __align__(16) __bf16 Bs[2][256 * 64];
  const int tid = threadIdx.x;
  const int w = tid >> 6, l = tid & 63;
  const int mt   = (int)gridDim.x >> 2;   // m-tiles (4 col-tiles)
  const int mper = mt >> 3;               // m-tiles per XCD
  const int xcd  = blockIdx.x & 7;
  const int idx  = blockIdx.x >> 3;
  const int brow = (xcd * mper + (idx >> 2)) * 256;  // chunk-local
  const int bcol = (idx & 3) * 256;
  const int lr = l & 15, lk = l >> 4;
  const int wm = w >> 2, wn = w & 3;          // 2M x 4N wave grid
  const int mbase = wm * 128, nbase = wn * 64;
  const int srow = w * 32 + (l >> 3);         // staging row (+ t*8)
  const int scol = (((l & 7) ^ ((l >> 3) & 7)) * 8);  // T2 inverse-swizzled source col
  const int swz  = (lr & 7) << 4;             // T2 read swizzle (byte XOR)
  const int NT = DIM / 64;                    // 8 K-steps
  f32x4 acc[8][4] = {};

  #define STAGE1(KT, BUF) do { \
    _Pragma("unroll") for (int t_ = 0; t_ < 4; ++t_) { \
      gload16(xb  + (size_t)(brow + srow + t_ * 8) * DIM + (KT) + scol, \
              As[BUF] + (w * 32 + t_ * 8) * 64); \
      gload16(w1t + (size_t)(bcol + srow + t_ * 8) * DIM + (KT) + scol, \
              Bs[BUF] + (w * 32 + t_ * 8) * 64); } } while (0)
  #define COMPUTE1(BUF) do { \
    _Pragma("unroll") for (int kk = 0; kk < 64; kk += 32) { \
      bf16x8 af[8], bq[4]; \
      _Pragma("unroll") for (int m = 0; m < 8; ++m) \
        af[m] = *(const bf16x8*)((const char*)(As[BUF]) + \
                 ((((mbase + m * 16 + lr) * 128) + kk * 2 + lk * 16) ^ swz)); \
      _Pragma("unroll") for (int nn = 0; nn < 4; ++nn) \
        bq[nn] = *(const bf16x8*)((const char*)(Bs[BUF]) + \
                 ((((nbase + nn * 16 + lr) * 128) + kk * 2 + lk * 16) ^ swz)); \
      __builtin_amdgcn_s_setprio(1); \
      _Pragma("unroll") for (int m = 0; m < 8; ++m) \
        _Pragma("unroll") for (int nn = 0; nn < 4; ++nn) \
          acc[m][nn] = __builtin_amdgcn_mfma_f32_16x16x32_bf16(af[m], bq[nn], acc[m][nn], 0, 0, 0); \
      __builtin_amdgcn_s_setprio(0); \
    } } while (0)

  STAGE1(0, 0);
  int cur = 0;
  for (int t = 0; t < NT - 1; ++t) {
    STAGE1((t + 1) * 64, cur ^ 1);                      // 8 loads stay in flight
    asm volatile("s_waitcnt vmcnt(8)" ::: "memory");    // tile t (oldest 8) done
    __builtin_amdgcn_s_barrier();                       // ready-barrier
    COMPUTE1(cur);
    __builtin_amdgcn_s_barrier();                       // free-barrier
    cur ^= 1;
  }
  asm volatile("s_waitcnt vmcnt(0)" ::: "memory");
  __builtin_amdgcn_s_barrier();
  COMPUTE1(cur);

  #undef STAGE1
  #undef COMPUTE1

  // epilogue: bias + relu + bf16 store
  #pragma unroll
  for (int nn = 0; nn < 4; ++nn) {
    const int col = bcol + nbase + nn * 16 + lr;
    const float bias = b1[col];
    #pragma unroll
    for (int m = 0; m < 8; ++m) {
      const int row = brow + mbase + m * 16 + lk * 4;   // chunk-local
      #pragma unroll
      for (int j = 0; j < 4; ++j) {
        float v = acc[m][nn][j] + bias;
        v = fmaxf(v, 0.f);
        h1[(size_t)(row + j) * H1DIM + col] = (__bf16)v;
      }
    }
  }
}

// ---------------- GEMM2 fused: y_u += relu(h1 @ W2 + b2) @ Wf ----------------
// Same structure. Grid 1-D: (Mc/256)*2 blocks.
__global__ __launch_bounds__(512, 2) void k_gemm2(const __bf16* __restrict__ h1,
                                                  const __bf16* __restrict__ w2t,
                                                  const float* __restrict__ b2,
                                                  const float* __restrict__ wf,
                                                  float* __restrict__ y_u, int row0) {
  __shared__ __align__(16) __bf16 As[2][256 * 64];
  __shared__ __align__(16) __bf16 Bs[2][256 * 64];
  __shared__ float yred[256];
  const int tid = threadIdx.x;
  const int w = tid >> 6, l = tid & 63;
  const int mt   = (int)gridDim.x >> 1;   // m-tiles (2 col-tiles)
  const int mper = mt >> 3;
  const int xcd  = blockIdx.x & 7;
  const int idx  = blockIdx.x >> 3;
  const int brow = (xcd * mper + (idx >> 1)) * 256;  // chunk-local
  const int n0   = (idx & 1) * 256;
  const int lr = l & 15, lk = l >> 4;
  const int wm = w >> 2, wn = w & 3;
  const int mbase = wm * 128, nbase = wn * 64;
  const int srow = w * 32 + (l >> 3);
  const int scol = (((l & 7) ^ ((l >> 3) & 7)) * 8);  // T2 inverse-swizzled source col
  const int swz  = (lr & 7) << 4;                     // T2 read swizzle
  const int NT = H1DIM / 64;              // 16 K-steps
  f32x4 acc[8][4] = {};

  #define STAGE2(KT, BUF) do { \
    _Pragma("unroll") for (int t_ = 0; t_ < 4; ++t_) { \
      gload16(h1  + (size_t)(brow + srow + t_ * 8) * H1DIM + (KT) + scol, \
              As[BUF] + (w * 32 + t_ * 8) * 64); \
      gload16(w2t + (size_t)(n0   + srow + t_ * 8) * H1DIM + (KT) + scol, \
              Bs[BUF] + (w * 32 + t_ * 8) * 64); } } while (0)
  #define COMPUTE2(BUF) do { \
    _Pragma("unroll") for (int kk = 0; kk < 64; kk += 32) { \
      bf16x8 af[8], bq[4]; \
      _Pragma("unroll") for (int m = 0; m < 8; ++m) \
        af[m] = *(const bf16x8*)((const char*)(As[BUF]) + \
                 ((((mbase + m * 16 + lr) * 128) + kk * 2 + lk * 16) ^ swz)); \
      _Pragma("unroll") for (int nn = 0; nn < 4; ++nn) \
        bq[nn] = *(const bf16x8*)((const char*)(Bs[BUF]) + \
                 ((((nbase + nn * 16 + lr) * 128) + kk * 2 + lk * 16) ^ swz)); \
      __builtin_amdgcn_s_setprio(1); \
      _Pragma("unroll") for (int m = 0; m < 8; ++m) \
        _Pragma("unroll") for (int nn = 0; nn < 4; ++nn) \
          acc[m][nn] = __builtin_amdgcn_mfma_f32_16x16x32_bf16(af[m], bq[nn], acc[m][nn], 0, 0, 0); \
      __builtin_amdgcn_s_setprio(0); \
    } } while (0)

  STAGE2(0, 0);
  int cur = 0;
  for (int t = 0; t < NT - 1; ++t) {
    STAGE2((t + 1) * 64, cur ^ 1);
    asm volatile("s_waitcnt vmcnt(8)" ::: "memory");
    __builtin_amdgcn_s_barrier();
    COMPUTE2(cur);
    __builtin_amdgcn_s_barrier();
    cur ^= 1;
  }
  asm volatile("s_waitcnt vmcnt(0)" ::: "memory");
  __builtin_amdgcn_s_barrier();
  COMPUTE2(cur);

  #undef STAGE2
  #undef COMPUTE2

  // epilogue: relu + dot with Wf over this block's 256 h2-columns
  float yacc[8][4] = {};
  #pragma unroll
  for (int nn = 0; nn < 4; ++nn) {
    const int col = n0 + nbase + nn * 16 + lr;
    const float bias = b2[col];
    const float wfv = wf[col];
    #pragma unroll
    for (int m = 0; m < 8; ++m)
      #pragma unroll
      for (int j = 0; j < 4; ++j)
        yacc[m][j] += fmaxf(acc[m][nn][j] + bias, 0.f) * wfv;
  }
  #pragma unroll
  for (int m = 0; m < 8; ++m)
    #pragma unroll
    for (int j = 0; j < 4; ++j) {
      float v = yacc[m][j];
      v += __shfl_xor(v, 1, 64);
      v += __shfl_xor(v, 2, 64);
      v += __shfl_xor(v, 4, 64);
      v += __shfl_xor(v, 8, 64);
      yacc[m][j] = v;
    }
  if (tid < 256) yred[tid] = 0.f;
  __syncthreads();
  if (lr == 0) {
    #pragma unroll
    for (int m = 0; m < 8; ++m)
      #pragma unroll
      for (int j = 0; j < 4; ++j)
        atomicAdd(&yred[mbase + m * 16 + lk * 4 + j], yacc[m][j]);
  }
  __syncthreads();
  if (tid < 256) atomicAdd(&y_u[row0 + brow + tid], yred[tid]);
}

// ---------------- projection: scatter per-group compacted (z0, 1/w) ----------------
// Two-phase block-aggregated compaction (R6 structure, 256 blocks).
__global__ __launch_bounds__(256) void k_scatter(const float* __restrict__ y_u,
                                                 const float* __restrict__ c,
                                                 const float* __restrict__ mask,
                                                 const float* __restrict__ bfp,
                                                 float* __restrict__ z0c, float* __restrict__ iwc,
                                                 unsigned char* __restrict__ gidx,
                                                 int* __restrict__ cnt, int n) {
  __shared__ int lcnt[NGRP];
  __shared__ int lbase[NGRP];
  const float bf0 = bfp[0];
  const int tid = threadIdx.x;
  if (tid < NGRP) lcnt[tid] = 0;
  __syncthreads();
  const int i = blockIdx.x * blockDim.x + tid;
  int g = 0, slot_l = 0;
  float z0 = 0.f, iw = 0.f;
  if (i < n) {
    const float cv = c[i];
    z0 = (y_u[i] + bf0) / cv - 1.f;
    iw = 1.f / (cv * cv);
    #pragma unroll
    for (int j = 1; j < NGRP; ++j)
      if (mask[(size_t)j * NROWS + i] > 0.5f) g = j;
    slot_l = atomicAdd(&lcnt[g], 1);      // LDS atomic: cheap
    gidx[i] = (unsigned char)g;
  }
  __syncthreads();
  if (tid < NGRP) lbase[tid] = atomicAdd(&cnt[tid], lcnt[tid]);  // 8 global atomics/block
  __syncthreads();
  if (i < n) {
    const int slot = lbase[g] + slot_l;
    if (slot < CAPG) {
      z0c[(size_t)g * CAPG + slot] = z0;
      iwc[(size_t)g * CAPG + slot] = iw;
    }
  }
}

// ---------------- joint (sum,sum) block reduction ----------------
__device__ __forceinline__ void red2(float& a, float& b, float* reda, float* redb, int tid) {
  #pragma unroll
  for (int o = 32; o > 0; o >>= 1) {
    a += __shfl_xor(a, o, 64);
    b += __shfl_xor(b, o, 64);
  }
  if ((tid & 63) == 0) { reda[tid >> 6] = a; redb[tid >> 6] = b; }
  __syncthreads();
  if (tid < 64) {
    float x = (tid < 16) ? reda[tid] : 0.f;
    float y = (tid < 16) ? redb[tid] : 0.f;
    #pragma unroll
    for (int o = 32; o > 0; o >>= 1) {
      x += __shfl_xor(x, o, 64);
      y += __shfl_xor(y, o, 64);
    }
    if (tid == 0) { reda[0] = x; redb[0] = y; }
  }
  __syncthreads();
  a = reda[0]; b = redb[0];
  __syncthreads();
}

// ---------------- per-group KKT multiplier via safeguarded Newton ----------------
// m(mu) = (1/n) sum clip(z0_i - mu*iw_i, +-EPS): monotone piecewise-linear.
// Newton with bisection fallback: 12 iterations >> enough.
__global__ __launch_bounds__(1024) void k_mu(const float* __restrict__ z0c,
                                             const float* __restrict__ iwc,
                                             const int* __restrict__ cnt,
                                             float* __restrict__ muarr) {
  __shared__ float reda[16], redb[16];
  const int g = blockIdx.x;
  const int tid = threadIdx.x;
  int n = cnt[g];
  if (n > CAPG) n = CAPG;
  if (n <= 0) { if (tid == 0) muarr[g] = 0.f; return; }
  float z0v[16], iwv[16];
  float hmax = -1e30f, hmin = 1e30f;
  #pragma unroll
  for (int t = 0; t < 16; ++t) {
    const int idx = t * 1024 + tid;
    if (idx < n) {
      const float z0 = z0c[(size_t)g * CAPG + idx];
      const float iw = iwc[(size_t)g * CAPG + idx];
      z0v[t] = z0; iwv[t] = iw;
      const float wv = 1.f / iw;
      hmax = fmaxf(hmax, (z0 + EPSC) * wv);
      hmin = fminf(hmin, (z0 - EPSC) * wv);
    } else { z0v[t] = 0.f; iwv[t] = 0.f; }
  }
  const float inv_n = 1.f / (float)n;
  #define EVAL2(MU, MS, DS) do { \
    float s_ = 0.f, d_ = 0.f; \
    _Pragma("unroll") for (int t_ = 0; t_ < 16; ++t_) { \
      float zz_ = z0v[t_] - (MU) * iwv[t_]; \
      if (zz_ > EPSC) zz_ = EPSC; \
      else if (zz_ < -EPSC) zz_ = -EPSC; \
      else d_ += iwv[t_]; \
      s_ += zz_; } \
    red2(s_, d_, reda, redb, tid); \
    MS = s_ * inv_n; DS = d_ * inv_n; \
  } while (0)
  float m0, d0;
  EVAL2(0.f, m0, d0);
  float mu = 0.f;
  if (fabsf(m0) > DELTA) {
    // bracket ends (block max of hmax, min of hmin) — reduce jointly as maxes
    float hx = hmax, hn = -hmin;
    #pragma unroll
    for (int o = 32; o > 0; o >>= 1) {
      hx = fmaxf(hx, __shfl_xor(hx, o, 64));
      hn = fmaxf(hn, __shfl_xor(hn, o, 64));
    }
    if ((tid & 63) == 0) { reda[tid >> 6] = hx; redb[tid >> 6] = hn; }
    __syncthreads();
    if (tid < 64) {
      float x = (tid < 16) ? reda[tid] : -1e30f;
      float y = (tid < 16) ? redb[tid] : -1e30f;
      #pragma unroll
      for (int o = 32; o > 0; o >>= 1) {
        x = fmaxf(x, __shfl_xor(x, o, 64));
        y = fmaxf(y, __shfl_xor(y, o, 64));
      }
      if (tid == 0) { reda[0] = x; redb[0] = y; }
    }
    __syncthreads();
    const float hmax_r = reda[0], hmin_r = -redb[0];
    __syncthreads();
    float target, lo, hi;
    if (m0 > 0.f) { target = DELTA;  lo = 0.f;    hi = hmax_r; }
    else          { target = -DELTA; lo = hmin_r; hi = 0.f;    }
    // first Newton step from mu=0 (m0, d0 known)
    mu = (d0 > 0.f) ? (m0 - target) / d0 : 0.5f * (lo + hi);
    if (!(mu > lo && mu < hi)) mu = 0.5f * (lo + hi);
    for (int it = 0; it < 12; ++it) {
      float mm, dd;
      EVAL2(mu, mm, dd);
      if (mm >= target) lo = mu; else hi = mu;
      float nm = (dd > 0.f) ? mu + (mm - target) / dd : 0.5f * (lo + hi);
      if (!(nm > lo && nm < hi)) nm = 0.5f * (lo + hi);
      mu = nm;
    }
  }
  if (tid == 0) muarr[g] = mu;
  #undef EVAL2
}

// ---------------- final: y = (clip(z0 - mu/w, +-EPS) + 1) * c ----------------
__global__ void k_y(const float* __restrict__ y_u, const float* __restrict__ c,
                    const float* __restrict__ bfp, const unsigned char* __restrict__ gidx,
                    const float* __restrict__ muarr, float* __restrict__ out, int n) {
  const float bf0 = bfp[0];
  int i = blockIdx.x * blockDim.x + threadIdx.x;
  const int stride = gridDim.x * blockDim.x;
  for (; i < n; i += stride) {
    const float cv = c[i];
    const float z0 = (y_u[i] + bf0) / cv - 1.f;
    const float mu = muarr[gidx[i]];
    const float z = fminf(fmaxf(z0 - mu / (cv * cv), -EPSC), EPSC);
    out[i] = (z + 1.f) * cv;
  }
}

extern "C" void kernel_launch(void* const* d_in, const int* in_sizes, int n_in,
                              void* d_out, int out_size, void* d_ws, size_t ws_size,
                              hipStream_t stream) {
  const float* x    = (const float*)d_in[0];
  const float* W1   = (const float*)d_in[1];
  const float* b1   = (const float*)d_in[2];
  const float* W2   = (const float*)d_in[3];
  const float* b2   = (const float*)d_in[4];
  const float* Wf   = (const float*)d_in[5];
  const float* bfp  = (const float*)d_in[6];
  const float* c    = (const float*)d_in[7];
  const float* mask = (const float*)d_in[8];
  float* out = (float*)d_out;

  char* ws = (char*)d_ws;
  size_t off = 0;
  auto alloc = [&](size_t bytes) -> void* {
    void* p = ws + off;
    off += (bytes + 255) & ~(size_t)255;
    return p;
  };
  __bf16* w1t = (__bf16*)alloc((size_t)H1DIM * DIM * 2);
  __bf16* w2t = (__bf16*)alloc((size_t)H2DIM * H1DIM * 2);
  float* y_u  = (float*)alloc((size_t)NROWS * 4);
  float* z0c  = (float*)alloc((size_t)NGRP * CAPG * 4);
  float* iwc  = (float*)alloc((size_t)NGRP * CAPG * 4);
  unsigned char* gidx = (unsigned char*)alloc(NROWS);
  int*   cnt  = (int*)alloc(NGRP * 4);
  float* muarr = (float*)alloc(NGRP * 4);
  const size_t fixed = off;

  // per-chunk buffers: xb (1 KB/row) + h1 (2 KB/row) = 3 KB/row.
  // Chunk must be a multiple of 2048 rows (256-row tiles, m-tiles % 8 == 0).
  size_t avail = (ws_size > fixed) ? (ws_size - fixed) : 0;
  long long rc = (long long)(avail / ((size_t)(DIM * 2 + H1DIM * 2)));
  rc &= ~2047LL;
  if (rc > 32768) rc = 32768;
  if (rc < 2048) rc = 2048;   // below this ws is insufficient; assume harness gives enough
  const int rows_chunk = (int)rc;
  __bf16* xb = (__bf16*)(ws + fixed);
  __bf16* h1 = (__bf16*)(ws + fixed + (size_t)rows_chunk * DIM * 2);

  k_tcvt<<<dim3(DIM / 32, H1DIM / 32), dim3(32, 8), 0, stream>>>(W1, w1t, DIM, H1DIM);
  k_tcvt<<<dim3(H1DIM / 32, H2DIM / 32), dim3(32, 8), 0, stream>>>(W2, w2t, H1DIM, H2DIM);

  bool first = true;
  for (int r0 = 0; r0 < NROWS; r0 += rows_chunk) {
    const int Mc = (NROWS - r0 < rows_chunk) ? (NROWS - r0) : rows_chunk;
    const int mtiles = Mc / 256;
    const int n8 = Mc * (DIM / 8);
    int cblocks = (n8 + 255) / 256; if (cblocks > 2048) cblocks = 2048;
    k_cvt_x<<<dim3(cblocks), dim3(256), 0, stream>>>(
        (const float4*)(x + (size_t)r0 * DIM), (bf16x8*)xb, n8,
        y_u, first ? NROWS : 0, cnt);
    first = false;
    k_gemm1<<<dim3(mtiles * 4), dim3(512), 0, stream>>>(xb, w1t, b1, h1);
    k_gemm2<<<dim3(mtiles * 2), dim3(512), 0, stream>>>(h1, w2t, b2, Wf, y_u, r0);
  }

  k_scatter<<<dim3((NROWS + 255) / 256), dim3(256), 0, stream>>>(y_u, c, mask, bfp, z0c, iwc, gidx, cnt, NROWS);
  k_mu<<<dim3(NGRP), dim3(1024), 0, stream>>>(z0c, iwc, cnt, muarr);
  k_y<<<dim3(256), dim3(256), 0, stream>>>(y_u, c, bfp, gidx, muarr, out, NROWS);
}

// Round 11
// 230.999 us; speedup vs baseline: 1.2119x; 1.0030x over previous
//
#include <hip/hip_runtime.h>
#include <hip/hip_bf16.h>

// Problem constants (fixed by the reference)
#define NROWS 65536
#define DIM   512
#define H1DIM 1024
#define H2DIM 512
#define EPSC  0.15f
#define DELTA 0.05f
#define NGRP  8
#define CAPG  16384   // per-group compacted capacity (actual ~8192)

typedef __bf16 bf16x8 __attribute__((ext_vector_type(8)));
typedef float  f32x4  __attribute__((ext_vector_type(4)));

__device__ __forceinline__ void gload16(const void* g, void* lds) {
  __builtin_amdgcn_global_load_lds((__attribute__((address_space(1))) const unsigned int*)g,
                                   (__attribute__((address_space(3))) unsigned int*)lds,
                                   16, 0, 0);
}

// ---------------- transpose + fp32->bf16 for BOTH weights in one launch ----------------
// blocks [0, 512): W1 (512x1024 -> w1t 1024x512); blocks [512, 1024): W2 (1024x512 -> w2t)
__global__ void k_tcvt2(const float* __restrict__ W1, __bf16* __restrict__ w1t,
                        const float* __restrict__ W2, __bf16* __restrict__ w2t) {
  __shared__ float tile[32][33];
  const float* src; __bf16* dst; int R, C, bid;
  if (blockIdx.x < 512) { src = W1; dst = w1t; R = DIM;   C = H1DIM; bid = blockIdx.x; }
  else                  { src = W2; dst = w2t; R = H1DIM; C = H2DIM; bid = blockIdx.x - 512; }
  const int bx = C / 32;                 // blocks along columns
  const int bi = (bid / bx) * 32;        // row base in src
  const int bj = (bid % bx) * 32;        // col base in src
  const int tx = threadIdx.x, ty = threadIdx.y;   // block (32,8)
  #pragma unroll
  for (int r = ty; r < 32; r += 8)
    tile[r][tx] = src[(size_t)(bi + r) * C + bj + tx];
  __syncthreads();
  #pragma unroll
  for (int r = ty; r < 32; r += 8)
    dst[(size_t)(bj + r) * R + bi + tx] = (__bf16)tile[tx][r];
}

// ---------------- x fp32 -> bf16 (2x float4 -> bf16x8) + y_u/cnt zeroing ----------------
__global__ __launch_bounds__(256) void k_cvt_x(const float4* __restrict__ x4,
                                               bf16x8* __restrict__ xb8, int n8,
                                               float* __restrict__ y_u, int zn,
                                               int* __restrict__ cnt) {
  const int stride = gridDim.x * blockDim.x;
  const int tid0 = blockIdx.x * blockDim.x + threadIdx.x;
  for (int i = tid0; i < n8; i += stride) {
    const float4 a = x4[2 * i];
    const float4 b = x4[2 * i + 1];
    bf16x8 v;
    v[0] = (__bf16)a.x; v[1] = (__bf16)a.y; v[2] = (__bf16)a.z; v[3] = (__bf16)a.w;
    v[4] = (__bf16)b.x; v[5] = (__bf16)b.y; v[6] = (__bf16)b.z; v[7] = (__bf16)b.w;
    xb8[i] = v;
  }
  for (int j = tid0; j < zn; j += stride) y_u[j] = 0.f;
  if (zn > 0 && tid0 < NGRP) cnt[tid0] = 0;
}

// ============ R6/R10 GEMMs (best measured structure): 256x256 / BK=64 / 8-wave dbuf ============
// T2 swizzle (both-sides): linear gload_lds dest + inverse-swizzled source col
// (slot' = (l&7)^((l>>3)&7)) + read byte-XOR ((lr&7)<<4).
// T4: STAGE(t+1) issued before s_waitcnt vmcnt(8) — 8 loads in flight across barrier.

// ---------------- GEMM1: h1 = relu(xb @ W1 + b1), bf16 in/out ----------------
// Grid 1-D: (Mc/256)*4 blocks, XCD-chunked swizzle, n-fastest.
__global__ __launch_bounds__(512, 2) void k_gemm1(const __bf16* __restrict__ xb,
                                                  const __bf16* __restrict__ w1t,
                                                  const float* __restrict__ b1,
                                                  __bf16* __restrict__ h1) {
  __shared__ __align__(16) __bf16 As[2][256 * 64];
  __shared__ __align__(16) __bf16 Bs[2][256 * 64];
  const int tid = threadIdx.x;
  const int w = tid >> 6, l = tid & 63;
  const int mt   = (int)gridDim.x >> 2;   // m-tiles (4 col-tiles)
  const int mper = mt >> 3;               // m-tiles per XCD
  const int xcd  = blockIdx.x & 7;
  const int idx  = blockIdx.x >> 3;
  const int brow = (xcd * mper + (idx >> 2)) * 256;
  const int bcol = (idx & 3) * 256;
  const int lr = l & 15, lk = l >> 4;
  const int wm = w >> 2, wn = w & 3;          // 2M x 4N wave grid
  const int mbase = wm * 128, nbase = wn * 64;
  const int srow = w * 32 + (l >> 3);         // staging row (+ t*8)
  const int scol = (((l & 7) ^ ((l >> 3) & 7)) * 8);  // T2 inverse-swizzled source col
  const int swz  = (lr & 7) << 4;             // T2 read swizzle (byte XOR)
  const int NT = DIM / 64;                    // 8 K-steps
  f32x4 acc[8][4] = {};

  #define STAGE1(KT, BUF) do { \
    _Pragma("unroll") for (int t_ = 0; t_ < 4; ++t_) { \
      gload16(xb  + (size_t)(brow + srow + t_ * 8) * DIM + (KT) + scol, \
              As[BUF] + (w * 32 + t_ * 8) * 64); \
      gload16(w1t + (size_t)(bcol + srow + t_ * 8) * DIM + (KT) + scol, \
              Bs[BUF] + (w * 32 + t_ * 8) * 64); } } while (0)
  #define COMPUTE1(BUF) do { \
    _Pragma("unroll") for (int kk = 0; kk < 64; kk += 32) { \
      bf16x8 af[8], bq[4]; \
      _Pragma("unroll") for (int m = 0; m < 8; ++m) \
        af[m] = *(const bf16x8*)((const char*)(As[BUF]) + \
                 ((((mbase + m * 16 + lr) * 128) + kk * 2 + lk * 16) ^ swz)); \
      _Pragma("unroll") for (int nn = 0; nn < 4; ++nn) \
        bq[nn] = *(const bf16x8*)((const char*)(Bs[BUF]) + \
                 ((((nbase + nn * 16 + lr) * 128) + kk * 2 + lk * 16) ^ swz)); \
      __builtin_amdgcn_s_setprio(1); \
      _Pragma("unroll") for (int m = 0; m < 8; ++m) \
        _Pragma("unroll") for (int nn = 0; nn < 4; ++nn) \
          acc[m][nn] = __builtin_amdgcn_mfma_f32_16x16x32_bf16(af[m], bq[nn], acc[m][nn], 0, 0, 0); \
      __builtin_amdgcn_s_setprio(0); \
    } } while (0)

  STAGE1(0, 0);
  int cur = 0;
  for (int t = 0; t < NT - 1; ++t) {
    STAGE1((t + 1) * 64, cur ^ 1);                      // 8 loads stay in flight
    asm volatile("s_waitcnt vmcnt(8)" ::: "memory");    // tile t (oldest 8) done
    __builtin_amdgcn_s_barrier();                       // ready-barrier
    COMPUTE1(cur);
    __builtin_amdgcn_s_barrier();                       // free-barrier
    cur ^= 1;
  }
  asm volatile("s_waitcnt vmcnt(0)" ::: "memory");
  __builtin_amdgcn_s_barrier();
  COMPUTE1(cur);

  #undef STAGE1
  #undef COMPUTE1

  // epilogue: bias + relu + bf16 store
  #pragma unroll
  for (int nn = 0; nn < 4; ++nn) {
    const int col = bcol + nbase + nn * 16 + lr;
    const float bias = b1[col];
    #pragma unroll
    for (int m = 0; m < 8; ++m) {
      const int row = brow + mbase + m * 16 + lk * 4;
      #pragma unroll
      for (int j = 0; j < 4; ++j) {
        float v = acc[m][nn][j] + bias;
        v = fmaxf(v, 0.f);
        h1[(size_t)(row + j) * H1DIM + col] = (__bf16)v;
      }
    }
  }
}

// ---------------- GEMM2 fused: y_u += relu(h1 @ W2 + b2) @ Wf ----------------
// Same structure. Grid 1-D: (Mc/256)*2 blocks.
__global__ __launch_bounds__(512, 2) void k_gemm2(const __bf16* __restrict__ h1,
                                                  const __bf16* __restrict__ w2t,
                                                  const float* __restrict__ b2,
                                                  const float* __restrict__ wf,
                                                  float* __restrict__ y_u) {
  __shared__ __align__(16) __bf16 As[2][256 * 64];
  __shared__ __align__(16) __bf16 Bs[2][256 * 64];
  __shared__ float yred[256];
  const int tid = threadIdx.x;
  const int w = tid >> 6, l = tid & 63;
  const int mt   = (int)gridDim.x >> 1;   // m-tiles (2 col-tiles)
  const int mper = mt >> 3;
  const int xcd  = blockIdx.x & 7;
  const int idx  = blockIdx.x >> 3;
  const int brow = (xcd * mper + (idx >> 1)) * 256;
  const int n0   = (idx & 1) * 256;
  const int lr = l & 15, lk = l >> 4;
  const int wm = w >> 2, wn = w & 3;
  const int mbase = wm * 128, nbase = wn * 64;
  const int srow = w * 32 + (l >> 3);
  const int scol = (((l & 7) ^ ((l >> 3) & 7)) * 8);
  const int swz  = (lr & 7) << 4;
  const int NT = H1DIM / 64;              // 16 K-steps
  f32x4 acc[8][4] = {};

  #define STAGE2(KT, BUF) do { \
    _Pragma("unroll") for (int t_ = 0; t_ < 4; ++t_) { \
      gload16(h1  + (size_t)(brow + srow + t_ * 8) * H1DIM + (KT) + scol, \
              As[BUF] + (w * 32 + t_ * 8) * 64); \
      gload16(w2t + (size_t)(n0   + srow + t_ * 8) * H1DIM + (KT) + scol, \
              Bs[BUF] + (w * 32 + t_ * 8) * 64); } } while (0)
  #define COMPUTE2(BUF) do { \
    _Pragma("unroll") for (int kk = 0; kk < 64; kk += 32) { \
      bf16x8 af[8], bq[4]; \
      _Pragma("unroll") for (int m = 0; m < 8; ++m) \
        af[m] = *(const bf16x8*)((const char*)(As[BUF]) + \
                 ((((mbase + m * 16 + lr) * 128) + kk * 2 + lk * 16) ^ swz)); \
      _Pragma("unroll") for (int nn = 0; nn < 4; ++nn) \
        bq[nn] = *(const bf16x8*)((const char*)(Bs[BUF]) + \
                 ((((nbase + nn * 16 + lr) * 128) + kk * 2 + lk * 16) ^ swz)); \
      __builtin_amdgcn_s_setprio(1); \
      _Pragma("unroll") for (int m = 0; m < 8; ++m) \
        _Pragma("unroll") for (int nn = 0; nn < 4; ++nn) \
          acc[m][nn] = __builtin_amdgcn_mfma_f32_16x16x32_bf16(af[m], bq[nn], acc[m][nn], 0, 0, 0); \
      __builtin_amdgcn_s_setprio(0); \
    } } while (0)

  STAGE2(0, 0);
  int cur = 0;
  for (int t = 0; t < NT - 1; ++t) {
    STAGE2((t + 1) * 64, cur ^ 1);
    asm volatile("s_waitcnt vmcnt(8)" ::: "memory");
    __builtin_amdgcn_s_barrier();
    COMPUTE2(cur);
    __builtin_amdgcn_s_barrier();
    cur ^= 1;
  }
  asm volatile("s_waitcnt vmcnt(0)" ::: "memory");
  __builtin_amdgcn_s_barrier();
  COMPUTE2(cur);

  #undef STAGE2
  #undef COMPUTE2

  // epilogue: relu + dot with Wf over this block's 256 h2-columns
  float yacc[8][4] = {};
  #pragma unroll
  for (int nn = 0; nn < 4; ++nn) {
    const int col = n0 + nbase + nn * 16 + lr;
    const float bias = b2[col];
    const float wfv = wf[col];
    #pragma unroll
    for (int m = 0; m < 8; ++m)
      #pragma unroll
      for (int j = 0; j < 4; ++j)
        yacc[m][j] += fmaxf(acc[m][nn][j] + bias, 0.f) * wfv;
  }
  #pragma unroll
  for (int m = 0; m < 8; ++m)
    #pragma unroll
    for (int j = 0; j < 4; ++j) {
      float v = yacc[m][j];
      v += __shfl_xor(v, 1, 64);
      v += __shfl_xor(v, 2, 64);
      v += __shfl_xor(v, 4, 64);
      v += __shfl_xor(v, 8, 64);
      yacc[m][j] = v;
    }
  if (tid < 256) yred[tid] = 0.f;
  __syncthreads();
  if (lr == 0) {
    #pragma unroll
    for (int m = 0; m < 8; ++m)
      #pragma unroll
      for (int j = 0; j < 4; ++j)
        atomicAdd(&yred[mbase + m * 16 + lk * 4 + j], yacc[m][j]);
  }
  __syncthreads();
  if (tid < 256) atomicAdd(&y_u[brow + tid], yred[tid]);
}

// ---------------- projection: scatter per-group compacted (z0, 1/w) ----------------
__global__ __launch_bounds__(256) void k_scatter(const float* __restrict__ y_u,
                                                 const float* __restrict__ c,
                                                 const float* __restrict__ mask,
                                                 const float* __restrict__ bfp,
                                                 float* __restrict__ z0c, float* __restrict__ iwc,
                                                 unsigned char* __restrict__ gidx,
                                                 int* __restrict__ cnt, int n) {
  __shared__ int lcnt[NGRP];
  __shared__ int lbase[NGRP];
  const float bf0 = bfp[0];
  const int tid = threadIdx.x;
  if (tid < NGRP) lcnt[tid] = 0;
  __syncthreads();
  const int i = blockIdx.x * blockDim.x + tid;
  int g = 0, slot_l = 0;
  float z0 = 0.f, iw = 0.f;
  if (i < n) {
    const float cv = c[i];
    z0 = (y_u[i] + bf0) / cv - 1.f;
    iw = 1.f / (cv * cv);
    #pragma unroll
    for (int j = 1; j < NGRP; ++j)
      if (mask[(size_t)j * NROWS + i] > 0.5f) g = j;
    slot_l = atomicAdd(&lcnt[g], 1);
    gidx[i] = (unsigned char)g;
  }
  __syncthreads();
  if (tid < NGRP) lbase[tid] = atomicAdd(&cnt[tid], lcnt[tid]);
  __syncthreads();
  if (i < n) {
    const int slot = lbase[g] + slot_l;
    if (slot < CAPG) {
      z0c[(size_t)g * CAPG + slot] = z0;
      iwc[(size_t)g * CAPG + slot] = iw;
    }
  }
}

// ---------------- joint (sum,sum) block reduction ----------------
__device__ __forceinline__ void red2(float& a, float& b, float* reda, float* redb, int tid) {
  #pragma unroll
  for (int o = 32; o > 0; o >>= 1) {
    a += __shfl_xor(a, o, 64);
    b += __shfl_xor(b, o, 64);
  }
  if ((tid & 63) == 0) { reda[tid >> 6] = a; redb[tid >> 6] = b; }
  __syncthreads();
  if (tid < 64) {
    float x = (tid < 16) ? reda[tid] : 0.f;
    float y = (tid < 16) ? redb[tid] : 0.f;
    #pragma unroll
    for (int o = 32; o > 0; o >>= 1) {
      x += __shfl_xor(x, o, 64);
      y += __shfl_xor(y, o, 64);
    }
    if (tid == 0) { reda[0] = x; redb[0] = y; }
  }
  __syncthreads();
  a = reda[0]; b = redb[0];
  __syncthreads();
}

// ---------------- per-group KKT multiplier via safeguarded Newton ----------------
__global__ __launch_bounds__(1024) void k_mu(const float* __restrict__ z0c,
                                             const float* __restrict__ iwc,
                                             const int* __restrict__ cnt,
                                             float* __restrict__ muarr) {
  __shared__ float reda[16], redb[16];
  const int g = blockIdx.x;
  const int tid = threadIdx.x;
  int n = cnt[g];
  if (n > CAPG) n = CAPG;
  if (n <= 0) { if (tid == 0) muarr[g] = 0.f; return; }
  float z0v[16], iwv[16];
  float hmax = -1e30f, hmin = 1e30f;
  #pragma unroll
  for (int t = 0; t < 16; ++t) {
    const int idx = t * 1024 + tid;
    if (idx < n) {
      const float z0 = z0c[(size_t)g * CAPG + idx];
      const float iw = iwc[(size_t)g * CAPG + idx];
      z0v[t] = z0; iwv[t] = iw;
      const float wv = 1.f / iw;
      hmax = fmaxf(hmax, (z0 + EPSC) * wv);
      hmin = fminf(hmin, (z0 - EPSC) * wv);
    } else { z0v[t] = 0.f; iwv[t] = 0.f; }
  }
  const float inv_n = 1.f / (float)n;
  #define EVAL2(MU, MS, DS) do { \
    float s_ = 0.f, d_ = 0.f; \
    _Pragma("unroll") for (int t_ = 0; t_ < 16; ++t_) { \
      float zz_ = z0v[t_] - (MU) * iwv[t_]; \
      if (zz_ > EPSC) zz_ = EPSC; \
      else if (zz_ < -EPSC) zz_ = -EPSC; \
      else d_ += iwv[t_]; \
      s_ += zz_; } \
    red2(s_, d_, reda, redb, tid); \
    MS = s_ * inv_n; DS = d_ * inv_n; \
  } while (0)
  float m0, d0;
  EVAL2(0.f, m0, d0);
  float mu = 0.f;
  if (fabsf(m0) > DELTA) {
    float hx = hmax, hn = -hmin;
    #pragma unroll
    for (int o = 32; o > 0; o >>= 1) {
      hx = fmaxf(hx, __shfl_xor(hx, o, 64));
      hn = fmaxf(hn, __shfl_xor(hn, o, 64));
    }
    if ((tid & 63) == 0) { reda[tid >> 6] = hx; redb[tid >> 6] = hn; }
    __syncthreads();
    if (tid < 64) {
      float x = (tid < 16) ? reda[tid] : -1e30f;
      float y = (tid < 16) ? redb[tid] : -1e30f;
      #pragma unroll
      for (int o = 32; o > 0; o >>= 1) {
        x = fmaxf(x, __shfl_xor(x, o, 64));
        y = fmaxf(y, __shfl_xor(y, o, 64));
      }
      if (tid == 0) { reda[0] = x; redb[0] = y; }
    }
    __syncthreads();
    const float hmax_r = reda[0], hmin_r = -redb[0];
    __syncthreads();
    float target, lo, hi;
    if (m0 > 0.f) { target = DELTA;  lo = 0.f;    hi = hmax_r; }
    else          { target = -DELTA; lo = hmin_r; hi = 0.f;    }
    mu = (d0 > 0.f) ? (m0 - target) / d0 : 0.5f * (lo + hi);
    if (!(mu > lo && mu < hi)) mu = 0.5f * (lo + hi);
    for (int it = 0; it < 9; ++it) {
      float mm, dd;
      EVAL2(mu, mm, dd);
      if (mm >= target) lo = mu; else hi = mu;
      float nm = (dd > 0.f) ? mu + (mm - target) / dd : 0.5f * (lo + hi);
      if (!(nm > lo && nm < hi)) nm = 0.5f * (lo + hi);
      mu = nm;
    }
  }
  if (tid == 0) muarr[g] = mu;
  #undef EVAL2
}

// ---------------- final: y = (clip(z0 - mu/w, +-EPS) + 1) * c ----------------
__global__ void k_y(const float* __restrict__ y_u, const float* __restrict__ c,
                    const float* __restrict__ bfp, const unsigned char* __restrict__ gidx,
                    const float* __restrict__ muarr, float* __restrict__ out, int n) {
  const float bf0 = bfp[0];
  int i = blockIdx.x * blockDim.x + threadIdx.x;
  const int stride = gridDim.x * blockDim.x;
  for (; i < n; i += stride) {
    const float cv = c[i];
    const float z0 = (y_u[i] + bf0) / cv - 1.f;
    const float mu = muarr[gidx[i]];
    const float z = fminf(fmaxf(z0 - mu / (cv * cv), -EPSC), EPSC);
    out[i] = (z + 1.f) * cv;
  }
}

extern "C" void kernel_launch(void* const* d_in, const int* in_sizes, int n_in,
                              void* d_out, int out_size, void* d_ws, size_t ws_size,
                              hipStream_t stream) {
  const float* x    = (const float*)d_in[0];
  const float* W1   = (const float*)d_in[1];
  const float* b1   = (const float*)d_in[2];
  const float* W2   = (const float*)d_in[3];
  const float* b2   = (const float*)d_in[4];
  const float* Wf   = (const float*)d_in[5];
  const float* bfp  = (const float*)d_in[6];
  const float* c    = (const float*)d_in[7];
  const float* mask = (const float*)d_in[8];
  float* out = (float*)d_out;

  char* ws = (char*)d_ws;
  size_t off = 0;
  auto alloc = [&](size_t bytes) -> void* {
    void* p = ws + off;
    off += (bytes + 255) & ~(size_t)255;
    return p;
  };
  __bf16* w1t = (__bf16*)alloc((size_t)H1DIM * DIM * 2);
  __bf16* w2t = (__bf16*)alloc((size_t)H2DIM * H1DIM * 2);
  float* y_u  = (float*)alloc((size_t)NROWS * 4);
  float* z0c  = (float*)alloc((size_t)NGRP * CAPG * 4);
  float* iwc  = (float*)alloc((size_t)NGRP * CAPG * 4);
  unsigned char* gidx = (unsigned char*)alloc(NROWS);
  int*   cnt  = (int*)alloc(NGRP * 4);
  float* muarr = (float*)alloc(NGRP * 4);
  const size_t fixed = off;

  // per-chunk buffers: xb (1 KB/row) + h1 (2 KB/row) = 3 KB/row.
  // Single chunk when ws permits (65536 rows = 192 MB); multiple of 2048 rows.
  size_t avail = (ws_size > fixed) ? (ws_size - fixed) : 0;
  long long rc = (long long)(avail / ((size_t)(DIM * 2 + H1DIM * 2)));
  rc &= ~2047LL;
  if (rc > NROWS) rc = NROWS;
  if (rc < 2048) rc = 2048;   // below this ws is insufficient; assume harness gives enough
  const int rows_chunk = (int)rc;
  __bf16* xb = (__bf16*)(ws + fixed);
  __bf16* h1 = (__bf16*)(ws + fixed + (size_t)rows_chunk * DIM * 2);

  k_tcvt2<<<dim3(1024), dim3(32, 8), 0, stream>>>(W1, w1t, W2, w2t);

  bool first = true;
  for (int r0 = 0; r0 < NROWS; r0 += rows_chunk) {
    const int Mc = (NROWS - r0 < rows_chunk) ? (NROWS - r0) : rows_chunk;
    const int mtiles = Mc / 256;
    const int n8 = Mc * (DIM / 8);
    int cblocks = (n8 + 255) / 256; if (cblocks > 2048) cblocks = 2048;
    k_cvt_x<<<dim3(cblocks), dim3(256), 0, stream>>>(
        (const float4*)(x + (size_t)r0 * DIM), (bf16x8*)xb, n8,
        y_u, first ? NROWS : 0, cnt);
    first = false;
    k_gemm1<<<dim3(mtiles * 4), dim3(512), 0, stream>>>(xb, w1t, b1, h1);
    k_gemm2<<<dim3(mtiles * 2), dim3(512), 0, stream>>>(h1, w2t, b2, Wf, y_u + r0);
  }

  k_scatter<<<dim3((NROWS + 255) / 256), dim3(256), 0, stream>>>(y_u, c, mask, bfp, z0c, iwc, gidx, cnt, NROWS);
  k_mu<<<dim3(NGRP), dim3(1024), 0, stream>>>(z0c, iwc, cnt, muarr);
  k_y<<<dim3(256), dim3(256), 0, stream>>>(y_u, c, bfp, gidx, muarr, out, NROWS);
}

// Round 12
// 219.957 us; speedup vs baseline: 1.2727x; 1.0502x over previous
//
#include <hip/hip_runtime.h>
#include <hip/hip_bf16.h>

// Problem constants (fixed by the reference)
#define NROWS 65536
#define DIM   512
#define H1DIM 1024
#define H2DIM 512
#define EPSC  0.15f
#define DELTA 0.05f
#define NGRP  8
#define CAPG  16384   // per-group compacted capacity (actual ~8192)

typedef __bf16 bf16x8 __attribute__((ext_vector_type(8)));
typedef float  f32x4  __attribute__((ext_vector_type(4)));

__device__ __forceinline__ void gload16(const void* g, void* lds) {
  __builtin_amdgcn_global_load_lds((__attribute__((address_space(1))) const unsigned int*)g,
                                   (__attribute__((address_space(3))) unsigned int*)lds,
                                   16, 0, 0);
}

// ---------------- transpose + fp32->bf16 for BOTH weights in one launch ----------------
__global__ void k_tcvt2(const float* __restrict__ W1, __bf16* __restrict__ w1t,
                        const float* __restrict__ W2, __bf16* __restrict__ w2t) {
  __shared__ float tile[32][33];
  const float* src; __bf16* dst; int R, C, bid;
  if (blockIdx.x < 512) { src = W1; dst = w1t; R = DIM;   C = H1DIM; bid = blockIdx.x; }
  else                  { src = W2; dst = w2t; R = H1DIM; C = H2DIM; bid = blockIdx.x - 512; }
  const int bx = C / 32;
  const int bi = (bid / bx) * 32;
  const int bj = (bid % bx) * 32;
  const int tx = threadIdx.x, ty = threadIdx.y;
  #pragma unroll
  for (int r = ty; r < 32; r += 8)
    tile[r][tx] = src[(size_t)(bi + r) * C + bj + tx];
  __syncthreads();
  #pragma unroll
  for (int r = ty; r < 32; r += 8)
    dst[(size_t)(bj + r) * R + bi + tx] = (__bf16)tile[tx][r];
}

// ---------------- x fp32 -> bf16 (2x float4 -> bf16x8) + y_u/cnt zeroing ----------------
__global__ __launch_bounds__(256) void k_cvt_x(const float4* __restrict__ x4,
                                               bf16x8* __restrict__ xb8, int n8,
                                               float* __restrict__ y_u, int zn,
                                               int* __restrict__ cnt) {
  const int stride = gridDim.x * blockDim.x;
  const int tid0 = blockIdx.x * blockDim.x + threadIdx.x;
  for (int i = tid0; i < n8; i += stride) {
    const float4 a = x4[2 * i];
    const float4 b = x4[2 * i + 1];
    bf16x8 v;
    v[0] = (__bf16)a.x; v[1] = (__bf16)a.y; v[2] = (__bf16)a.z; v[3] = (__bf16)a.w;
    v[4] = (__bf16)b.x; v[5] = (__bf16)b.y; v[6] = (__bf16)b.z; v[7] = (__bf16)b.w;
    xb8[i] = v;
  }
  for (int j = tid0; j < zn; j += stride) y_u[j] = 0.f;
  if (zn > 0 && tid0 < NGRP) cnt[tid0] = 0;
}

// ============ 256x256 / BK=64 / 8-wave dbuf GEMMs, 4-phase FINE-SPREAD pipeline ============
// Wave tiling aligned to staged half-tiles: A rows = mhalf*128 + wm*64 + sub*16 + lr,
// B cols = nhalf*128 + wn*32 + sub*16 + lr. Phase units: P0:{A0,B0} P1:{B1} P2:{A1} P3:{}.
// Stage 1 unit (2 gload16/thread) per phase, order A0,B0,B1,A1; counted vmcnt(4) at ends
// of P0/P1/P3 (4-6 loads always in flight, never drained). One barrier per phase; MFMA
// after the barrier so other waves' ds_read/stage overlap it (setprio role-diversity).
// T2 swizzle unchanged: stage source col slot' = (l&7)^((l>>3)&7), read byte-XOR (lr&7)<<4.

#define RD_A(ARR, BUF, MH) do { \
  _Pragma("unroll") for (int kk_ = 0; kk_ < 2; ++kk_) \
    _Pragma("unroll") for (int m_ = 0; m_ < 4; ++m_) \
      aR[kk_][m_] = *(const bf16x8*)((const char*)(ARR[BUF]) + \
        (((((MH) * 128 + wm * 64 + m_ * 16 + lr) * 128) + kk_ * 64 + lk * 16) ^ swz)); \
} while (0)
#define RD_B(ARR, BUF, NH) do { \
  _Pragma("unroll") for (int kk_ = 0; kk_ < 2; ++kk_) \
    _Pragma("unroll") for (int n_ = 0; n_ < 2; ++n_) \
      bR[(NH) * 2 + n_][kk_] = *(const bf16x8*)((const char*)(ARR[BUF]) + \
        (((((NH) * 128 + wn * 32 + n_ * 16 + lr) * 128) + kk_ * 64 + lk * 16) ^ swz)); \
} while (0)
#define MFMA_Q(MH, NH) do { \
  __builtin_amdgcn_s_setprio(1); \
  _Pragma("unroll") for (int kk_ = 0; kk_ < 2; ++kk_) \
    _Pragma("unroll") for (int m_ = 0; m_ < 4; ++m_) \
      _Pragma("unroll") for (int n_ = 0; n_ < 2; ++n_) \
        acc[(MH) * 4 + m_][(NH) * 2 + n_] = __builtin_amdgcn_mfma_f32_16x16x32_bf16( \
            aR[kk_][m_], bR[(NH) * 2 + n_][kk_], acc[(MH) * 4 + m_][(NH) * 2 + n_], 0, 0, 0); \
  __builtin_amdgcn_s_setprio(0); \
} while (0)
#define VM4 asm volatile("s_waitcnt vmcnt(4)" ::: "memory")
#define BAR __builtin_amdgcn_s_barrier()

// ---------------- GEMM1: h1 = relu(xb @ W1 + b1) ----------------
__global__ __launch_bounds__(512, 2) void k_gemm1(const __bf16* __restrict__ xb,
                                                  const __bf16* __restrict__ w1t,
                                                  const float* __restrict__ b1,
                                                  __bf16* __restrict__ h1) {
  __shared__ __align__(16) __bf16 As[2][256 * 64];
  __shared__ __align__(16) __bf16 Bs[2][256 * 64];
  const int tid = threadIdx.x;
  const int w = tid >> 6, l = tid & 63;
  const int mt   = (int)gridDim.x >> 2;
  const int mper = mt >> 3;
  const int xcd  = blockIdx.x & 7;
  const int idx  = blockIdx.x >> 3;
  const int brow = (xcd * mper + (idx >> 2)) * 256;
  const int bcol = (idx & 3) * 256;
  const int lr = l & 15, lk = l >> 4;
  const int wm = w >> 2, wn = w & 3;
  const int srow8 = w * 8 + (l >> 3);               // staging row within 64-row round
  const int scol  = ((l & 7) ^ ((l >> 3) & 7)) * 8; // swizzled source col
  const int swz   = (lr & 7) << 4;                  // read swizzle
  const int NT = DIM / 64;                          // 8 K-tiles
  f32x4 acc[8][4] = {};
  bf16x8 aR[2][4], bR[4][2];

  #define STG_A1(KT, BUF, H) do { \
    gload16(xb + (size_t)(brow + (H) * 128 + srow8) * DIM + (KT) + scol, \
            As[BUF] + ((H) * 128 + w * 8) * 64); \
    gload16(xb + (size_t)(brow + (H) * 128 + 64 + srow8) * DIM + (KT) + scol, \
            As[BUF] + ((H) * 128 + 64 + w * 8) * 64); } while (0)
  #define STG_B1(KT, BUF, H) do { \
    gload16(w1t + (size_t)(bcol + (H) * 128 + srow8) * DIM + (KT) + scol, \
            Bs[BUF] + ((H) * 128 + w * 8) * 64); \
    gload16(w1t + (size_t)(bcol + (H) * 128 + 64 + srow8) * DIM + (KT) + scol, \
            Bs[BUF] + ((H) * 128 + 64 + w * 8) * 64); } while (0)

  // prologue: tile 0, issue order A0,B0,B1,A1; wait for A0,B0
  STG_A1(0, 0, 0); STG_B1(0, 0, 0); STG_B1(0, 0, 1); STG_A1(0, 0, 1);
  VM4; BAR;
  int cur = 0;
  for (int t = 0; t < NT; ++t) {
    const int ktn = (t + 1) * 64;
    const bool pre = (t + 1 < NT);
    // P0: quadrant (A0,B0)
    RD_A(As, cur, 0); RD_B(Bs, cur, 0);
    if (pre) { STG_A1(ktn, cur ^ 1, 0); VM4; }
    else     { asm volatile("s_waitcnt vmcnt(2)" ::: "memory"); }
    BAR;
    MFMA_Q(0, 0);
    // P1: quadrant (A0,B1)
    RD_B(Bs, cur, 1);
    if (pre) { STG_B1(ktn, cur ^ 1, 0); VM4; }
    else     { asm volatile("s_waitcnt vmcnt(0)" ::: "memory"); }
    BAR;
    MFMA_Q(0, 1);
    // P2: quadrant (A1,B1)
    RD_A(As, cur, 1);
    if (pre) STG_B1(ktn, cur ^ 1, 1);
    BAR;
    MFMA_Q(1, 1);
    // P3: quadrant (A1,B0) — register-retained, no ds_read
    if (pre) { STG_A1(ktn, cur ^ 1, 1); VM4; }
    BAR;
    MFMA_Q(1, 0);
    cur ^= 1;
  }
  #undef STG_A1
  #undef STG_B1

  // epilogue: bias + relu + bf16 store (half-aligned wave tiling)
  #pragma unroll
  for (int nn = 0; nn < 4; ++nn) {
    const int col = bcol + (nn >> 1) * 128 + wn * 32 + (nn & 1) * 16 + lr;
    const float bias = b1[col];
    #pragma unroll
    for (int m = 0; m < 8; ++m) {
      const int row = brow + (m >> 2) * 128 + wm * 64 + (m & 3) * 16 + lk * 4;
      #pragma unroll
      for (int j = 0; j < 4; ++j) {
        float v = acc[m][nn][j] + bias;
        h1[(size_t)(row + j) * H1DIM + col] = (__bf16)fmaxf(v, 0.f);
      }
    }
  }
}

// ---------------- GEMM2 fused: y_u += relu(h1 @ W2 + b2) @ Wf ----------------
__global__ __launch_bounds__(512, 2) void k_gemm2(const __bf16* __restrict__ h1,
                                                  const __bf16* __restrict__ w2t,
                                                  const float* __restrict__ b2,
                                                  const float* __restrict__ wf,
                                                  float* __restrict__ y_u) {
  __shared__ __align__(16) __bf16 As[2][256 * 64];
  __shared__ __align__(16) __bf16 Bs[2][256 * 64];
  __shared__ float yred[256];
  const int tid = threadIdx.x;
  const int w = tid >> 6, l = tid & 63;
  const int mt   = (int)gridDim.x >> 1;
  const int mper = mt >> 3;
  const int xcd  = blockIdx.x & 7;
  const int idx  = blockIdx.x >> 3;
  const int brow = (xcd * mper + (idx >> 1)) * 256;
  const int n0   = (idx & 1) * 256;
  const int lr = l & 15, lk = l >> 4;
  const int wm = w >> 2, wn = w & 3;
  const int srow8 = w * 8 + (l >> 3);
  const int scol  = ((l & 7) ^ ((l >> 3) & 7)) * 8;
  const int swz   = (lr & 7) << 4;
  const int NT = H1DIM / 64;                        // 16 K-tiles
  f32x4 acc[8][4] = {};
  bf16x8 aR[2][4], bR[4][2];

  #define STG_A2(KT, BUF, H) do { \
    gload16(h1 + (size_t)(brow + (H) * 128 + srow8) * H1DIM + (KT) + scol, \
            As[BUF] + ((H) * 128 + w * 8) * 64); \
    gload16(h1 + (size_t)(brow + (H) * 128 + 64 + srow8) * H1DIM + (KT) + scol, \
            As[BUF] + ((H) * 128 + 64 + w * 8) * 64); } while (0)
  #define STG_B2(KT, BUF, H) do { \
    gload16(w2t + (size_t)(n0 + (H) * 128 + srow8) * H1DIM + (KT) + scol, \
            Bs[BUF] + ((H) * 128 + w * 8) * 64); \
    gload16(w2t + (size_t)(n0 + (H) * 128 + 64 + srow8) * H1DIM + (KT) + scol, \
            Bs[BUF] + ((H) * 128 + 64 + w * 8) * 64); } while (0)

  STG_A2(0, 0, 0); STG_B2(0, 0, 0); STG_B2(0, 0, 1); STG_A2(0, 0, 1);
  VM4; BAR;
  int cur = 0;
  for (int t = 0; t < NT; ++t) {
    const int ktn = (t + 1) * 64;
    const bool pre = (t + 1 < NT);
    RD_A(As, cur, 0); RD_B(Bs, cur, 0);
    if (pre) { STG_A2(ktn, cur ^ 1, 0); VM4; }
    else     { asm volatile("s_waitcnt vmcnt(2)" ::: "memory"); }
    BAR;
    MFMA_Q(0, 0);
    RD_B(Bs, cur, 1);
    if (pre) { STG_B2(ktn, cur ^ 1, 0); VM4; }
    else     { asm volatile("s_waitcnt vmcnt(0)" ::: "memory"); }
    BAR;
    MFMA_Q(0, 1);
    RD_A(As, cur, 1);
    if (pre) STG_B2(ktn, cur ^ 1, 1);
    BAR;
    MFMA_Q(1, 1);
    if (pre) { STG_A2(ktn, cur ^ 1, 1); VM4; }
    BAR;
    MFMA_Q(1, 0);
    cur ^= 1;
  }
  #undef STG_A2
  #undef STG_B2

  // epilogue: relu + dot with Wf over this block's 256 h2-columns
  float yacc[8][4] = {};
  #pragma unroll
  for (int nn = 0; nn < 4; ++nn) {
    const int col = n0 + (nn >> 1) * 128 + wn * 32 + (nn & 1) * 16 + lr;
    const float bias = b2[col];
    const float wfv = wf[col];
    #pragma unroll
    for (int m = 0; m < 8; ++m)
      #pragma unroll
      for (int j = 0; j < 4; ++j)
        yacc[m][j] += fmaxf(acc[m][nn][j] + bias, 0.f) * wfv;
  }
  #pragma unroll
  for (int m = 0; m < 8; ++m)
    #pragma unroll
    for (int j = 0; j < 4; ++j) {
      float v = yacc[m][j];
      v += __shfl_xor(v, 1, 64);
      v += __shfl_xor(v, 2, 64);
      v += __shfl_xor(v, 4, 64);
      v += __shfl_xor(v, 8, 64);
      yacc[m][j] = v;
    }
  if (tid < 256) yred[tid] = 0.f;
  __syncthreads();
  if (lr == 0) {
    #pragma unroll
    for (int m = 0; m < 8; ++m)
      #pragma unroll
      for (int j = 0; j < 4; ++j)
        atomicAdd(&yred[(m >> 2) * 128 + wm * 64 + (m & 3) * 16 + lk * 4 + j], yacc[m][j]);
  }
  __syncthreads();
  if (tid < 256) atomicAdd(&y_u[brow + tid], yred[tid]);
}

#undef RD_A
#undef RD_B
#undef MFMA_Q
#undef VM4
#undef BAR

// ---------------- projection: scatter per-group compacted (z0, 1/w) ----------------
__global__ __launch_bounds__(256) void k_scatter(const float* __restrict__ y_u,
                                                 const float* __restrict__ c,
                                                 const float* __restrict__ mask,
                                                 const float* __restrict__ bfp,
                                                 float* __restrict__ z0c, float* __restrict__ iwc,
                                                 unsigned char* __restrict__ gidx,
                                                 int* __restrict__ cnt, int n) {
  __shared__ int lcnt[NGRP];
  __shared__ int lbase[NGRP];
  const float bf0 = bfp[0];
  const int tid = threadIdx.x;
  if (tid < NGRP) lcnt[tid] = 0;
  __syncthreads();
  const int i = blockIdx.x * blockDim.x + tid;
  int g = 0, slot_l = 0;
  float z0 = 0.f, iw = 0.f;
  if (i < n) {
    const float cv = c[i];
    z0 = (y_u[i] + bf0) / cv - 1.f;
    iw = 1.f / (cv * cv);
    #pragma unroll
    for (int j = 1; j < NGRP; ++j)
      if (mask[(size_t)j * NROWS + i] > 0.5f) g = j;
    slot_l = atomicAdd(&lcnt[g], 1);
    gidx[i] = (unsigned char)g;
  }
  __syncthreads();
  if (tid < NGRP) lbase[tid] = atomicAdd(&cnt[tid], lcnt[tid]);
  __syncthreads();
  if (i < n) {
    const int slot = lbase[g] + slot_l;
    if (slot < CAPG) {
      z0c[(size_t)g * CAPG + slot] = z0;
      iwc[(size_t)g * CAPG + slot] = iw;
    }
  }
}

// ---------------- joint (sum,sum) block reduction ----------------
__device__ __forceinline__ void red2(float& a, float& b, float* reda, float* redb, int tid) {
  #pragma unroll
  for (int o = 32; o > 0; o >>= 1) {
    a += __shfl_xor(a, o, 64);
    b += __shfl_xor(b, o, 64);
  }
  if ((tid & 63) == 0) { reda[tid >> 6] = a; redb[tid >> 6] = b; }
  __syncthreads();
  if (tid < 64) {
    float x = (tid < 16) ? reda[tid] : 0.f;
    float y = (tid < 16) ? redb[tid] : 0.f;
    #pragma unroll
    for (int o = 32; o > 0; o >>= 1) {
      x += __shfl_xor(x, o, 64);
      y += __shfl_xor(y, o, 64);
    }
    if (tid == 0) { reda[0] = x; redb[0] = y; }
  }
  __syncthreads();
  a = reda[0]; b = redb[0];
  __syncthreads();
}

// ---------------- per-group KKT multiplier via safeguarded Newton ----------------
__global__ __launch_bounds__(1024) void k_mu(const float* __restrict__ z0c,
                                             const float* __restrict__ iwc,
                                             const int* __restrict__ cnt,
                                             float* __restrict__ muarr) {
  __shared__ float reda[16], redb[16];
  const int g = blockIdx.x;
  const int tid = threadIdx.x;
  int n = cnt[g];
  if (n > CAPG) n = CAPG;
  if (n <= 0) { if (tid == 0) muarr[g] = 0.f; return; }
  float z0v[16], iwv[16];
  float hmax = -1e30f, hmin = 1e30f;
  #pragma unroll
  for (int t = 0; t < 16; ++t) {
    const int idx = t * 1024 + tid;
    if (idx < n) {
      const float z0 = z0c[(size_t)g * CAPG + idx];
      const float iw = iwc[(size_t)g * CAPG + idx];
      z0v[t] = z0; iwv[t] = iw;
      const float wv = 1.f / iw;
      hmax = fmaxf(hmax, (z0 + EPSC) * wv);
      hmin = fminf(hmin, (z0 - EPSC) * wv);
    } else { z0v[t] = 0.f; iwv[t] = 0.f; }
  }
  const float inv_n = 1.f / (float)n;
  #define EVAL2(MU, MS, DS) do { \
    float s_ = 0.f, d_ = 0.f; \
    _Pragma("unroll") for (int t_ = 0; t_ < 16; ++t_) { \
      float zz_ = z0v[t_] - (MU) * iwv[t_]; \
      if (zz_ > EPSC) zz_ = EPSC; \
      else if (zz_ < -EPSC) zz_ = -EPSC; \
      else d_ += iwv[t_]; \
      s_ += zz_; } \
    red2(s_, d_, reda, redb, tid); \
    MS = s_ * inv_n; DS = d_ * inv_n; \
  } while (0)
  float m0, d0;
  EVAL2(0.f, m0, d0);
  float mu = 0.f;
  if (fabsf(m0) > DELTA) {
    float hx = hmax, hn = -hmin;
    #pragma unroll
    for (int o = 32; o > 0; o >>= 1) {
      hx = fmaxf(hx, __shfl_xor(hx, o, 64));
      hn = fmaxf(hn, __shfl_xor(hn, o, 64));
    }
    if ((tid & 63) == 0) { reda[tid >> 6] = hx; redb[tid >> 6] = hn; }
    __syncthreads();
    if (tid < 64) {
      float x = (tid < 16) ? reda[tid] : -1e30f;
      float y = (tid < 16) ? redb[tid] : -1e30f;
      #pragma unroll
      for (int o = 32; o > 0; o >>= 1) {
        x = fmaxf(x, __shfl_xor(x, o, 64));
        y = fmaxf(y, __shfl_xor(y, o, 64));
      }
      if (tid == 0) { reda[0] = x; redb[0] = y; }
    }
    __syncthreads();
    const float hmax_r = reda[0], hmin_r = -redb[0];
    __syncthreads();
    float target, lo, hi;
    if (m0 > 0.f) { target = DELTA;  lo = 0.f;    hi = hmax_r; }
    else          { target = -DELTA; lo = hmin_r; hi = 0.f;    }
    mu = (d0 > 0.f) ? (m0 - target) / d0 : 0.5f * (lo + hi);
    if (!(mu > lo && mu < hi)) mu = 0.5f * (lo + hi);
    for (int it = 0; it < 9; ++it) {
      float mm, dd;
      EVAL2(mu, mm, dd);
      if (mm >= target) lo = mu; else hi = mu;
      float nm = (dd > 0.f) ? mu + (mm - target) / dd : 0.5f * (lo + hi);
      if (!(nm > lo && nm < hi)) nm = 0.5f * (lo + hi);
      mu = nm;
    }
  }
  if (tid == 0) muarr[g] = mu;
  #undef EVAL2
}

// ---------------- final: y = (clip(z0 - mu/w, +-EPS) + 1) * c ----------------
__global__ void k_y(const float* __restrict__ y_u, const float* __restrict__ c,
                    const float* __restrict__ bfp, const unsigned char* __restrict__ gidx,
                    const float* __restrict__ muarr, float* __restrict__ out, int n) {
  const float bf0 = bfp[0];
  int i = blockIdx.x * blockDim.x + threadIdx.x;
  const int stride = gridDim.x * blockDim.x;
  for (; i < n; i += stride) {
    const float cv = c[i];
    const float z0 = (y_u[i] + bf0) / cv - 1.f;
    const float mu = muarr[gidx[i]];
    const float z = fminf(fmaxf(z0 - mu / (cv * cv), -EPSC), EPSC);
    out[i] = (z + 1.f) * cv;
  }
}

extern "C" void kernel_launch(void* const* d_in, const int* in_sizes, int n_in,
                              void* d_out, int out_size, void* d_ws, size_t ws_size,
                              hipStream_t stream) {
  const float* x    = (const float*)d_in[0];
  const float* W1   = (const float*)d_in[1];
  const float* b1   = (const float*)d_in[2];
  const float* W2   = (const float*)d_in[3];
  const float* b2   = (const float*)d_in[4];
  const float* Wf   = (const float*)d_in[5];
  const float* bfp  = (const float*)d_in[6];
  const float* c    = (const float*)d_in[7];
  const float* mask = (const float*)d_in[8];
  float* out = (float*)d_out;

  char* ws = (char*)d_ws;
  size_t off = 0;
  auto alloc = [&](size_t bytes) -> void* {
    void* p = ws + off;
    off += (bytes + 255) & ~(size_t)255;
    return p;
  };
  __bf16* w1t = (__bf16*)alloc((size_t)H1DIM * DIM * 2);
  __bf16* w2t = (__bf16*)alloc((size_t)H2DIM * H1DIM * 2);
  float* y_u  = (float*)alloc((size_t)NROWS * 4);
  float* z0c  = (float*)alloc((size_t)NGRP * CAPG * 4);
  float* iwc  = (float*)alloc((size_t)NGRP * CAPG * 4);
  unsigned char* gidx = (unsigned char*)alloc(NROWS);
  int*   cnt  = (int*)alloc(NGRP * 4);
  float* muarr = (float*)alloc(NGRP * 4);
  const size_t fixed = off;

  // per-chunk buffers: xb (1 KB/row) + h1 (2 KB/row) = 3 KB/row; single chunk when ws permits.
  size_t avail = (ws_size > fixed) ? (ws_size - fixed) : 0;
  long long rc = (long long)(avail / ((size_t)(DIM * 2 + H1DIM * 2)));
  rc &= ~2047LL;
  if (rc > NROWS) rc = NROWS;
  if (rc < 2048) rc = 2048;
  const int rows_chunk = (int)rc;
  __bf16* xb = (__bf16*)(ws + fixed);
  __bf16* h1 = (__bf16*)(ws + fixed + (size_t)rows_chunk * DIM * 2);

  k_tcvt2<<<dim3(1024), dim3(32, 8), 0, stream>>>(W1, w1t, W2, w2t);

  bool first = true;
  for (int r0 = 0; r0 < NROWS; r0 += rows_chunk) {
    const int Mc = (NROWS - r0 < rows_chunk) ? (NROWS - r0) : rows_chunk;
    const int mtiles = Mc / 256;
    const int n8 = Mc * (DIM / 8);
    int cblocks = (n8 + 255) / 256; if (cblocks > 2048) cblocks = 2048;
    k_cvt_x<<<dim3(cblocks), dim3(256), 0, stream>>>(
        (const float4*)(x + (size_t)r0 * DIM), (bf16x8*)xb, n8,
        y_u, first ? NROWS : 0, cnt);
    first = false;
    k_gemm1<<<dim3(mtiles * 4), dim3(512), 0, stream>>>(xb, w1t, b1, h1);
    k_gemm2<<<dim3(mtiles * 2), dim3(512), 0, stream>>>(h1, w2t, b2, Wf, y_u + r0);
  }

  k_scatter<<<dim3((NROWS + 255) / 256), dim3(256), 0, stream>>>(y_u, c, mask, bfp, z0c, iwc, gidx, cnt, NROWS);
  k_mu<<<dim3(NGRP), dim3(1024), 0, stream>>>(z0c, iwc, cnt, muarr);
  k_y<<<dim3(256), dim3(256), 0, stream>>>(y_u, c, bfp, gidx, muarr, out, NROWS);
}